// Round 6
// baseline (2307.963 us; speedup 1.0000x reference)
//
#include <hip/hip_runtime.h>
#include <hip/hip_bf16.h>
#include <math.h>

typedef __hip_bfloat16 bf16;

#define B_    16
#define HH    56
#define WW    56
#define LS    3136
#define CH    256
#define CG    64
#define NG    4
#define HID   1024
#define NCHK  49
#define CHL   64
#define EPSL  1e-5f

__device__ __forceinline__ float wsum64(float v){
  #pragma unroll
  for (int o=32;o;o>>=1) v += __shfl_xor(v,o);
  return v;
}
__device__ __forceinline__ float bf2f(unsigned short u){ return __uint_as_float(((unsigned)u)<<16); }
__device__ __forceinline__ float ldbf(const bf16* p){ return bf2f(*(const unsigned short*)p); }

// LayerNorm over 256 channels, one row per block; f32 in -> bf16 out
__global__ __launch_bounds__(256) void k_ln256(const float* __restrict__ x,
    const float* __restrict__ w, const float* __restrict__ b,
    bf16* __restrict__ out){
  size_t row = blockIdx.x;
  int t = threadIdx.x;
  float v = x[row*CH + t];
  float s = wsum64(v), s2 = wsum64(v*v);
  __shared__ float a1[4], a2[4];
  if ((t&63)==0){ a1[t>>6]=s; a2[t>>6]=s2; }
  __syncthreads();
  float S  = a1[0]+a1[1]+a1[2]+a1[3];
  float S2 = a2[0]+a2[1]+a2[2]+a2[3];
  float m = S*(1.f/CH);
  float var = S2*(1.f/CH) - m*m;
  out[row*CH + t] = __float2bfloat16((v-m)*rsqrtf(var+EPSL)*w[t] + b[t]);
}

// partial column means over bf16 xn
__global__ __launch_bounds__(256) void k_colmean(const bf16* __restrict__ xn,
    float* __restrict__ part){
  int b = blockIdx.x >> 5, chunk = blockIdx.x & 31;
  int t = threadIdx.x;
  size_t base = ((size_t)b*LS + chunk*98)*CH + t;
  float s = 0.f;
  for (int i=0;i<98;i++) s += ldbf(xn + base + (size_t)i*CH);
  part[(size_t)blockIdx.x*CH + t] = s;
}

// gate = sigmoid(z_avg @ fc_w.T + fc_b + conv1d(z_avg, ca_w))
__global__ __launch_bounds__(256) void k_gate(const float* __restrict__ part,
    const float* __restrict__ fcw, const float* __restrict__ fcb,
    const float* __restrict__ caw, float* __restrict__ gate){
  int b = blockIdx.x, t = threadIdx.x;
  __shared__ float za[CH];
  float s = 0.f;
  for (int k=0;k<32;k++) s += part[((size_t)b*32+k)*CH + t];
  float zv = s*(1.f/LS);
  za[t] = zv; __syncthreads();
  float acc = fcb[t];
  for (int k=0;k<CH;k++) acc += za[k]*fcw[(size_t)t*CH+k];
  float yca = caw[1]*zv;
  if (t>0)    yca += caw[0]*za[t-1];
  if (t<CH-1) yca += caw[2]*za[t+1];
  acc += yca;
  gate[b*CH+t] = 1.f/(1.f+expf(-acc));
}

// per-group in_proj: xz = xn_g @ W^T ; first 64 -> xcpre(bf16), last 64 -> silu -> sz(f32, lives on d_out)
__global__ __launch_bounds__(256) void k_inproj(const bf16* __restrict__ xn,
    const float* __restrict__ ipw, bf16* __restrict__ xcpre, float* __restrict__ sz){
  __shared__ float Xs[64][CG+1];
  __shared__ float Wsh[2*CG][CG+1];
  int t = threadIdx.x;
  int tile = blockIdx.x;
  int bg = blockIdx.y; int b = bg>>2, g = bg&3;
  const float* Wg = ipw + (size_t)g*2*CG*CG;
  for (int i=t;i<2*CG*CG;i+=256) Wsh[i>>6][i&63] = Wg[i];
  int n0 = tile*64;
  for (int i=t;i<64*CG;i+=256){
    int r=i>>6, j=i&63;
    Xs[r][j] = ldbf(xn + ((size_t)b*LS + n0+r)*CH + g*CG + j);
  }
  __syncthreads();
  int i0 = (t&31)*4;
  int r0 = (t>>5)*8;
  float acc[8][4];
  #pragma unroll
  for(int r=0;r<8;r++) for(int q=0;q<4;q++) acc[r][q]=0.f;
  for (int k=0;k<CG;k++){
    float wv[4];
    #pragma unroll
    for(int q=0;q<4;q++) wv[q]=Wsh[i0+q][k];
    #pragma unroll
    for(int r=0;r<8;r++){
      float xv = Xs[r0+r][k];
      #pragma unroll
      for(int q=0;q<4;q++) acc[r][q] += xv*wv[q];
    }
  }
  size_t obase = (size_t)bg*LS + n0 + r0;
  #pragma unroll
  for(int r=0;r<8;r++){
    #pragma unroll
    for(int q=0;q<4;q++){
      int i=i0+q; float v=acc[r][q];
      if (i<CG) xcpre[(obase+r)*CG + i] = __float2bfloat16(v);
      else      sz[(obase+r)*CG + (i-CG)] = v/(1.f+expf(-v));
    }
  }
}

// depthwise 3x3 SAME + bias + silu, scattered into scan order u[b,g,l,c] (bf16)
__global__ __launch_bounds__(256) void k_conv_u(const bf16* __restrict__ xcpre,
    const float* __restrict__ cw, const float* __restrict__ cb, bf16* __restrict__ u){
  int lin = blockIdx.x;
  int nt = lin % (LS/4); int bg = lin/(LS/4); int g = bg&3;
  int t = threadIdx.x; int c = t&63;
  int n = nt*4 + (t>>6);
  int h = n/WW, w = n%WW;
  const bf16* base = xcpre + (size_t)bg*LS*CG;
  float acc = cb[g*CG+c];
  #pragma unroll
  for (int dy=-1;dy<=1;dy++){
    int hh2=h+dy; if (hh2<0||hh2>=HH) continue;
    #pragma unroll
    for (int dx=-1;dx<=1;dx++){
      int ww2=w+dx; if (ww2<0||ww2>=WW) continue;
      acc += ldbf(base + ((size_t)(hh2*WW+ww2))*CG + c) * cw[((g*CG+c)*3+(dy+1))*3+(dx+1)];
    }
  }
  float v = acc/(1.f+expf(-acc));
  int l;
  if (g==0) l = n;
  else if (g==1) l = LS-1-n;
  else { int lt = w*HH + h; l = (g==2)? lt : (LS-1-lt); }
  u[((size_t)bg*LS + l)*CG + c] = __float2bfloat16(v);
}

// x_proj + dt_proj: store dt (bf16), Bs, Cs (f32 scalars per position); u kept pure
__global__ __launch_bounds__(256) void k_xdbl(const bf16* __restrict__ u,
    const float* __restrict__ xpw, const float* __restrict__ dtw,
    const float* __restrict__ dtbv, bf16* __restrict__ dt,
    float* __restrict__ Bs, float* __restrict__ Cs){
  int lin = blockIdx.x;
  int nt = lin % (LS/4); int bg = lin/(LS/4); int g = bg&3;
  int t = threadIdx.x; int c = t&63;
  int l = nt*4 + (t>>6);
  size_t idx = ((size_t)bg*LS + l)*CG + c;
  float uv = ldbf(u+idx);
  float red[6];
  #pragma unroll
  for (int r=0;r<6;r++) red[r] = wsum64(uv * xpw[(g*6+r)*CG + c]);
  float dtacc = dtbv[g*CG+c];
  #pragma unroll
  for (int r=0;r<4;r++) dtacc += red[r]*dtw[(g*CG+c)*4 + r];
  float d = (dtacc>20.f)? dtacc : log1pf(expf(dtacc));
  dt[idx] = __float2bfloat16(d);
  if (c==0){ Bs[(size_t)bg*LS + l] = red[4]; Cs[(size_t)bg*LS + l] = red[5]; }
}

// chunked scan pass 1: per-chunk (P = prod a, S = local scan); a,bm recomputed
__global__ __launch_bounds__(64) void k_scan1(const bf16* __restrict__ dt,
    const bf16* __restrict__ u, const float* __restrict__ Bs,
    const float* __restrict__ alog, float* __restrict__ Pb, float* __restrict__ Sb){
  int c = threadIdx.x;
  int k = blockIdx.x % NCHK; int bg = blockIdx.x / NCHK; int g = bg&3;
  float A = -expf(alog[g*CG+c]);
  size_t base = ((size_t)bg*LS + k*CHL)*CG + c;
  size_t lb = (size_t)bg*LS + k*CHL;
  float P=1.f, S=0.f;
  for (int i=0;i<CHL;i++){
    float d  = ldbf(dt + base + (size_t)i*CG);
    float uv = ldbf(u  + base + (size_t)i*CG);
    float a  = expf(d*A);
    S = a*S + d*Bs[lb+i]*uv; P *= a;
  }
  size_t o = ((size_t)bg*NCHK + k)*CG + c;
  Pb[o]=P; Sb[o]=S;
}

// pass 2: sequential combine of chunk summaries -> h_in per chunk
__global__ __launch_bounds__(64) void k_scan2(const float* __restrict__ Pb,
    const float* __restrict__ Sb, float* __restrict__ Hin){
  int c = threadIdx.x; int bg = blockIdx.x;
  float h = 0.f;
  for (int k=0;k<NCHK;k++){
    size_t o = ((size_t)bg*NCHK + k)*CG + c;
    Hin[o] = h;
    h = Pb[o]*h + Sb[o];
  }
}

// pass 3: final scan + y = h*Cs + Dp*u, fused out-norm LN, silu(z) mult, inverse map
__global__ __launch_bounds__(64) void k_scan3(const bf16* __restrict__ dt,
    const bf16* __restrict__ u, const float* __restrict__ Bs,
    const float* __restrict__ Cs, const float* __restrict__ Hin,
    const float* __restrict__ sz, const float* __restrict__ alog,
    const float* __restrict__ Dpp, const float* __restrict__ onw,
    const float* __restrict__ onb, bf16* __restrict__ ymid){
  int c = threadIdx.x;
  int k = blockIdx.x % NCHK; int bg = blockIdx.x / NCHK;
  int b = bg>>2, g = bg&3;
  float A  = -expf(alog[g*CG+c]);
  float dp = Dpp[g*CG+c];
  float wq = onw[g*CG+c], bq = onb[g*CG+c];
  float h = Hin[((size_t)bg*NCHK + k)*CG + c];
  for (int i=0;i<CHL;i++){
    int l = k*CHL + i;
    size_t idx = ((size_t)bg*LS + l)*CG + c;
    float d = ldbf(dt+idx), uv = ldbf(u+idx);
    float a = expf(d*A);
    h = a*h + d*Bs[(size_t)bg*LS+l]*uv;
    float y = h*Cs[(size_t)bg*LS+l] + dp*uv;
    float s = wsum64(y), s2 = wsum64(y*y);
    float m = s*(1.f/CG), var = s2*(1.f/CG) - m*m;
    float yn = (y-m)*rsqrtf(var+EPSL)*wq + bq;
    int n;
    if (g==0) n = l;
    else if (g==1) n = LS-1-l;
    else { int lt=(g==2)? l : (LS-1-l); n = (lt%HH)*WW + (lt/HH); }
    float szv = sz[((size_t)bg*LS + n)*CG + c];
    ymid[((size_t)b*LS + n)*CH + g*CG + c] = __float2bfloat16(yn*szv);
  }
}

// out_proj (64x64 reg-cached) + skip*xn*gate + LN(norm1) -> ymln (bf16)
__global__ __launch_bounds__(256) void k_mix(const bf16* __restrict__ ymid,
    const bf16* __restrict__ xn, const float* __restrict__ gate,
    const float* __restrict__ opw, const float* __restrict__ skip,
    const float* __restrict__ n1w, const float* __restrict__ n1b,
    bf16* __restrict__ ymln){
  int t = threadIdx.x; int g = t>>6, i = t&63;
  int b = blockIdx.x / (LS/8); int nt = blockIdx.x % (LS/8);
  float Wr[CG];
  const float* wp = opw + (size_t)(g*CG + i)*CG;
  #pragma unroll
  for (int k=0;k<CG;k++) Wr[k]=wp[k];
  float ss = skip[0];
  float gv = gate[b*CH + t];
  float w1 = n1w[t], b1 = n1b[t];
  __shared__ float row[CH];
  __shared__ float r1s[4], r2s[4];
  for (int r=0;r<8;r++){
    int n = nt*8 + r;
    __syncthreads();
    row[t] = ldbf(ymid + ((size_t)b*LS + n)*CH + t);
    __syncthreads();
    float o = 0.f;
    const float* rp = &row[g*CG];
    #pragma unroll
    for (int k=0;k<CG;k++) o += Wr[k]*rp[k];
    float val = o*ss*ldbf(xn + ((size_t)b*LS+n)*CH + t)*gv;
    float s = wsum64(val), s2 = wsum64(val*val);
    if ((t&63)==0){ r1s[t>>6]=s; r2s[t>>6]=s2; }
    __syncthreads();
    float S  = r1s[0]+r1s[1]+r1s[2]+r1s[3];
    float S2 = r2s[0]+r2s[1]+r2s[2]+r2s[3];
    float m = S*(1.f/CH), var = S2*(1.f/CH)-m*m;
    ymln[((size_t)b*LS+n)*CH + t] = __float2bfloat16((val-m)*rsqrtf(var+EPSL)*w1 + b1);
  }
}

// NT GEMM, A bf16 (M,K) lda=K, B f32 (N rows, ldb stride), C (M,N) ldc=N.
// v = acc + bias[n] + resid[m,n]; resid may alias Cp (same-thread RAW only).
template<int OBF16>
__global__ __launch_bounds__(256) void k_gemm(const bf16* __restrict__ A16,
    const float* __restrict__ Bw, int ldb, const float* __restrict__ bias,
    const float* __restrict__ resid, void* __restrict__ Cp,
    int M, int N, int K){
  __shared__ float As[64][17];
  __shared__ float Bsh[64][17];
  int t = threadIdx.x;
  int bx = blockIdx.x, by = blockIdx.y;
  int tn = t&15, tm = t>>4;
  float acc[4][4];
  #pragma unroll
  for(int i=0;i<4;i++) for(int j=0;j<4;j++) acc[i][j]=0.f;
  int r  = t>>2;
  int kk = (t&3)*4;
  for (int k0=0;k0<K;k0+=16){
    size_t aoff = (size_t)(by*64 + r)*K + k0 + kk;
    ushort4 a4 = *reinterpret_cast<const ushort4*>((const unsigned short*)A16 + aoff);
    As[r][kk+0]=bf2f(a4.x); As[r][kk+1]=bf2f(a4.y);
    As[r][kk+2]=bf2f(a4.z); As[r][kk+3]=bf2f(a4.w);
    size_t boff = (size_t)(bx*64 + r)*ldb + k0 + kk;
    float4 b4 = *reinterpret_cast<const float4*>(Bw + boff);
    Bsh[r][kk+0]=b4.x; Bsh[r][kk+1]=b4.y; Bsh[r][kk+2]=b4.z; Bsh[r][kk+3]=b4.w;
    __syncthreads();
    #pragma unroll
    for (int k=0;k<16;k++){
      float av[4], bv[4];
      #pragma unroll
      for(int q=0;q<4;q++) av[q]=As[tm*4+q][k];
      #pragma unroll
      for(int q=0;q<4;q++) bv[q]=Bsh[tn*4+q][k];
      #pragma unroll
      for(int i=0;i<4;i++)
        #pragma unroll
        for(int j=0;j<4;j++) acc[i][j] += av[i]*bv[j];
    }
    __syncthreads();
  }
  #pragma unroll
  for(int i=0;i<4;i++){
    size_t m = (size_t)by*64 + tm*4 + i;
    #pragma unroll
    for(int j=0;j<4;j++){
      int nn = bx*64 + tn*4 + j;
      float v = acc[i][j];
      if (bias)  v += bias[nn];
      if (resid) v += resid[m*N + nn];
      if (OBF16) ((bf16*)Cp)[m*N+nn] = __float2bfloat16(v);
      else       ((float*)Cp)[m*N+nn] = v;
    }
  }
}

// depthwise 3x3 on one hidden-quarter (256 ch) + exact GELU, bf16 in/out
__global__ __launch_bounds__(256) void k_dwgelu(const bf16* __restrict__ h1,
    const float* __restrict__ dww, const float* __restrict__ dwb, int q,
    bf16* __restrict__ h2){
  int lin = blockIdx.x;
  int b = lin / LS, n = lin % LS;
  int hh2 = n/WW, ww2 = n%WW;
  int t = threadIdx.x;
  int ch = q*256 + t;
  size_t rb = (size_t)b*LS;
  float acc = dwb[ch];
  #pragma unroll
  for (int dy=-1;dy<=1;dy++){
    int y=hh2+dy; if (y<0||y>=HH) continue;
    #pragma unroll
    for (int dx=-1;dx<=1;dx++){
      int x2=ww2+dx; if (x2<0||x2>=WW) continue;
      acc += ldbf(h1 + (rb + y*WW + x2)*CH + t) * dww[(ch*3+dy+1)*3 + dx+1];
    }
  }
  float gel = 0.5f*acc*(1.f + erff(acc*0.7071067811865475f));
  h2[(rb + n)*CH + t] = __float2bfloat16(gel);
}

extern "C" void kernel_launch(void* const* d_in, const int* in_sizes, int n_in,
                              void* d_out, int out_size, void* d_ws, size_t ws_size,
                              hipStream_t stream){
  const float* x    = (const float*)d_in[0];
  const float* n1w  = (const float*)d_in[1];
  const float* n1b  = (const float*)d_in[2];
  const float* fcw  = (const float*)d_in[3];
  const float* fcb  = (const float*)d_in[4];
  const float* caw  = (const float*)d_in[5];
  const float* skip = (const float*)d_in[6];
  const float* pw   = (const float*)d_in[7];
  const float* pb   = (const float*)d_in[8];
  const float* ipw  = (const float*)d_in[9];
  const float* cw   = (const float*)d_in[10];
  const float* cb   = (const float*)d_in[11];
  const float* xpw  = (const float*)d_in[12];
  const float* dtw  = (const float*)d_in[13];
  const float* dtb  = (const float*)d_in[14];
  const float* alog = (const float*)d_in[15];
  const float* Dp   = (const float*)d_in[16];
  const float* onw  = (const float*)d_in[17];
  const float* onb  = (const float*)d_in[18];
  const float* opw  = (const float*)d_in[19];
  const float* n2w  = (const float*)d_in[20];
  const float* n2b  = (const float*)d_in[21];
  const float* f1w  = (const float*)d_in[22];
  const float* f1b  = (const float*)d_in[23];
  const float* dww  = (const float*)d_in[24];
  const float* dwb  = (const float*)d_in[25];
  const float* f2w  = (const float*)d_in[26];
  const float* f2b  = (const float*)d_in[27];
  (void)in_sizes; (void)n_in; (void)out_size;

  const size_t HRE = (size_t)B_*LS*CH;   // 12,845,056 elems; bf16 region = 25.7 MB
  bf16* hb   = (bf16*)d_ws;
  bf16* xnb  = hb;             // HR0: xn            -> h1 (quarter)
  bf16* xcp  = hb + HRE;       // HR1: xcpre -> ymid -> h2 (quarter)
  bf16* ub   = hb + 2*HRE;     // HR2: u     -> ymln
  bf16* dtq  = hb + 3*HRE;     // HR3: dt    -> xn2
  float* sm  = (float*)(hb + 4*HRE);
  float* part= sm;             // 131072
  float* gate= sm + 131072;    // 4096
  float* Bs  = sm + 135168;    // 200704
  float* Cs  = sm + 335872;    // 200704
  float* Pb  = sm + 536576;    // 200704
  float* Sb  = sm + 737280;    // 200704
  float* Hin = sm + 937984;    // 200704  (small total = 1,138,688 f32)
  float* szf  = (float*)d_out; // d_out doubles as scratch: sz until scan3,
  float* xnew = (float*)d_out; // then x_new (residual) until the end.

  size_t need = 4*HRE*sizeof(bf16) + (size_t)1138688*sizeof(float); // 107,315,200 B
  if (ws_size < need){
    // diagnostic fallback: out=x -> absmax error != 5.625 distinguishes
    // "ws too small" from "pipeline wrote zeros"
    hipMemcpyAsync(d_out, (const void*)x, HRE*sizeof(float),
                   hipMemcpyDeviceToDevice, stream);
    return;
  }

  const int M = B_*LS;

  k_ln256  <<<M, 256, 0, stream>>>(x, n1w, n1b, xnb);
  k_colmean<<<B_*32, 256, 0, stream>>>(xnb, part);
  k_gate   <<<B_, 256, 0, stream>>>(part, fcw, fcb, caw, gate);
  k_inproj <<<dim3(49, B_*NG), 256, 0, stream>>>(xnb, ipw, xcp, szf);
  k_conv_u <<<B_*NG*(LS/4), 256, 0, stream>>>(xcp, cw, cb, ub);
  k_xdbl   <<<B_*NG*(LS/4), 256, 0, stream>>>(ub, xpw, dtw, dtb, dtq, Bs, Cs);
  k_scan1  <<<B_*NG*NCHK, 64, 0, stream>>>(dtq, ub, Bs, alog, Pb, Sb);
  k_scan2  <<<B_*NG, 64, 0, stream>>>(Pb, Sb, Hin);
  k_scan3  <<<B_*NG*NCHK, 64, 0, stream>>>(dtq, ub, Bs, Cs, Hin, szf, alog, Dp, onw, onb, xcp);
  k_mix    <<<B_*(LS/8), 256, 0, stream>>>(xcp, xnb, gate, opw, skip, n1w, n1b, ub);
  // proj GEMM: x_new = ymln @ pw^T + pb + x  -> d_out
  k_gemm<0><<<dim3(CH/64, M/64), 256, 0, stream>>>(ub, pw, CH, pb, x, xnew, M, CH, CH);
  // norm2 -> xn2 (bf16, HR3)
  k_ln256  <<<M, 256, 0, stream>>>(xnew, n2w, n2b, dtq);
  // MLP in hidden-quarters of 256: fc1 -> dwconv+gelu -> fc2 accumulate into d_out
  for (int q=0; q<4; ++q){
    k_gemm<1><<<dim3(4, M/64), 256, 0, stream>>>(dtq, f1w + (size_t)q*256*CH, CH,
                                                 f1b + q*256, nullptr, xnb, M, 256, CH);
    k_dwgelu <<<B_*LS, 256, 0, stream>>>(xnb, dww, dwb, q, xcp);
    k_gemm<0><<<dim3(4, M/64), 256, 0, stream>>>(xcp, f2w + q*256, HID,
                                                 (q==0)? f2b : nullptr, xnew, xnew, M, 256, 256);
  }
}

// Round 7
// 1374.765 us; speedup vs baseline: 1.6788x; 1.6788x over previous
//
#include <hip/hip_runtime.h>
#include <hip/hip_bf16.h>
#include <math.h>

typedef __hip_bfloat16 bf16;
typedef __attribute__((ext_vector_type(8))) short bf16x8;
typedef __attribute__((ext_vector_type(4))) float f32x4;

#define B_    16
#define HH    56
#define WW    56
#define LS    3136
#define CH    256
#define CG    64
#define NG    4
#define HID   1024
#define NCHK  49
#define CHL   64
#define EPSL  1e-5f

__device__ __forceinline__ float wsum64(float v){
  #pragma unroll
  for (int o=32;o;o>>=1) v += __shfl_xor(v,o);
  return v;
}
__device__ __forceinline__ float bf2f(unsigned short u){ return __uint_as_float(((unsigned)u)<<16); }
__device__ __forceinline__ float ldbf(const bf16* p){ return bf2f(*(const unsigned short*)p); }
__device__ __forceinline__ void g2l16(const void* g, void* l){
  __builtin_amdgcn_global_load_lds((const __attribute__((address_space(1))) void*)g,
                                   (__attribute__((address_space(3))) void*)l, 16, 0, 0);
}

// LayerNorm over 256 channels, one row per block; f32 in -> bf16 out
__global__ __launch_bounds__(256) void k_ln256(const float* __restrict__ x,
    const float* __restrict__ w, const float* __restrict__ b,
    bf16* __restrict__ out){
  size_t row = blockIdx.x;
  int t = threadIdx.x;
  float v = x[row*CH + t];
  float s = wsum64(v), s2 = wsum64(v*v);
  __shared__ float a1[4], a2[4];
  if ((t&63)==0){ a1[t>>6]=s; a2[t>>6]=s2; }
  __syncthreads();
  float S  = a1[0]+a1[1]+a1[2]+a1[3];
  float S2 = a2[0]+a2[1]+a2[2]+a2[3];
  float m = S*(1.f/CH);
  float var = S2*(1.f/CH) - m*m;
  out[row*CH + t] = __float2bfloat16((v-m)*rsqrtf(var+EPSL)*w[t] + b[t]);
}

// partial column means over bf16 xn
__global__ __launch_bounds__(256) void k_colmean(const bf16* __restrict__ xn,
    float* __restrict__ part){
  int b = blockIdx.x >> 5, chunk = blockIdx.x & 31;
  int t = threadIdx.x;
  size_t base = ((size_t)b*LS + chunk*98)*CH + t;
  float s = 0.f;
  for (int i=0;i<98;i++) s += ldbf(xn + base + (size_t)i*CH);
  part[(size_t)blockIdx.x*CH + t] = s;
}

// gate = sigmoid(z_avg @ fc_w.T + fc_b + conv1d(z_avg, ca_w))
__global__ __launch_bounds__(256) void k_gate(const float* __restrict__ part,
    const float* __restrict__ fcw, const float* __restrict__ fcb,
    const float* __restrict__ caw, float* __restrict__ gate){
  int b = blockIdx.x, t = threadIdx.x;
  __shared__ float za[CH];
  float s = 0.f;
  for (int k=0;k<32;k++) s += part[((size_t)b*32+k)*CH + t];
  float zv = s*(1.f/LS);
  za[t] = zv; __syncthreads();
  float acc = fcb[t];
  for (int k=0;k<CH;k++) acc += za[k]*fcw[(size_t)t*CH+k];
  float yca = caw[1]*zv;
  if (t>0)    yca += caw[0]*za[t-1];
  if (t<CH-1) yca += caw[2]*za[t+1];
  acc += yca;
  gate[b*CH+t] = 1.f/(1.f+expf(-acc));
}

// per-group in_proj: xz = xn_g @ W^T ; first 64 -> xcpre(bf16), last 64 -> silu -> sz(f32, lives on d_out)
__global__ __launch_bounds__(256) void k_inproj(const bf16* __restrict__ xn,
    const float* __restrict__ ipw, bf16* __restrict__ xcpre, float* __restrict__ sz){
  __shared__ float Xs[64][CG+1];
  __shared__ float Wsh[2*CG][CG+1];
  int t = threadIdx.x;
  int tile = blockIdx.x;
  int bg = blockIdx.y; int b = bg>>2, g = bg&3;
  const float* Wg = ipw + (size_t)g*2*CG*CG;
  for (int i=t;i<2*CG*CG;i+=256) Wsh[i>>6][i&63] = Wg[i];
  int n0 = tile*64;
  for (int i=t;i<64*CG;i+=256){
    int r=i>>6, j=i&63;
    Xs[r][j] = ldbf(xn + ((size_t)b*LS + n0+r)*CH + g*CG + j);
  }
  __syncthreads();
  int i0 = (t&31)*4;
  int r0 = (t>>5)*8;
  float acc[8][4];
  #pragma unroll
  for(int r=0;r<8;r++) for(int q=0;q<4;q++) acc[r][q]=0.f;
  for (int k=0;k<CG;k++){
    float wv[4];
    #pragma unroll
    for(int q=0;q<4;q++) wv[q]=Wsh[i0+q][k];
    #pragma unroll
    for(int r=0;r<8;r++){
      float xv = Xs[r0+r][k];
      #pragma unroll
      for(int q=0;q<4;q++) acc[r][q] += xv*wv[q];
    }
  }
  size_t obase = (size_t)bg*LS + n0 + r0;
  #pragma unroll
  for(int r=0;r<8;r++){
    #pragma unroll
    for(int q=0;q<4;q++){
      int i=i0+q; float v=acc[r][q];
      if (i<CG) xcpre[(obase+r)*CG + i] = __float2bfloat16(v);
      else      sz[(obase+r)*CG + (i-CG)] = v/(1.f+expf(-v));
    }
  }
}

// depthwise 3x3 SAME + bias + silu, scattered into scan order u[b,g,l,c] (bf16)
__global__ __launch_bounds__(256) void k_conv_u(const bf16* __restrict__ xcpre,
    const float* __restrict__ cw, const float* __restrict__ cb, bf16* __restrict__ u){
  int lin = blockIdx.x;
  int nt = lin % (LS/4); int bg = lin/(LS/4); int g = bg&3;
  int t = threadIdx.x; int c = t&63;
  int n = nt*4 + (t>>6);
  int h = n/WW, w = n%WW;
  const bf16* base = xcpre + (size_t)bg*LS*CG;
  float acc = cb[g*CG+c];
  #pragma unroll
  for (int dy=-1;dy<=1;dy++){
    int hh2=h+dy; if (hh2<0||hh2>=HH) continue;
    #pragma unroll
    for (int dx=-1;dx<=1;dx++){
      int ww2=w+dx; if (ww2<0||ww2>=WW) continue;
      acc += ldbf(base + ((size_t)(hh2*WW+ww2))*CG + c) * cw[((g*CG+c)*3+(dy+1))*3+(dx+1)];
    }
  }
  float v = acc/(1.f+expf(-acc));
  int l;
  if (g==0) l = n;
  else if (g==1) l = LS-1-n;
  else { int lt = w*HH + h; l = (g==2)? lt : (LS-1-lt); }
  u[((size_t)bg*LS + l)*CG + c] = __float2bfloat16(v);
}

// x_proj + dt_proj: store dt (bf16), Bs, Cs (f32 scalars per position); u kept pure
__global__ __launch_bounds__(256) void k_xdbl(const bf16* __restrict__ u,
    const float* __restrict__ xpw, const float* __restrict__ dtw,
    const float* __restrict__ dtbv, bf16* __restrict__ dt,
    float* __restrict__ Bs, float* __restrict__ Cs){
  int lin = blockIdx.x;
  int nt = lin % (LS/4); int bg = lin/(LS/4); int g = bg&3;
  int t = threadIdx.x; int c = t&63;
  int l = nt*4 + (t>>6);
  size_t idx = ((size_t)bg*LS + l)*CG + c;
  float uv = ldbf(u+idx);
  float red[6];
  #pragma unroll
  for (int r=0;r<6;r++) red[r] = wsum64(uv * xpw[(g*6+r)*CG + c]);
  float dtacc = dtbv[g*CG+c];
  #pragma unroll
  for (int r=0;r<4;r++) dtacc += red[r]*dtw[(g*CG+c)*4 + r];
  float d = (dtacc>20.f)? dtacc : log1pf(expf(dtacc));
  dt[idx] = __float2bfloat16(d);
  if (c==0){ Bs[(size_t)bg*LS + l] = red[4]; Cs[(size_t)bg*LS + l] = red[5]; }
}

// chunked scan pass 1: per-chunk (P = prod a, S = local scan); a,bm recomputed
__global__ __launch_bounds__(64) void k_scan1(const bf16* __restrict__ dt,
    const bf16* __restrict__ u, const float* __restrict__ Bs,
    const float* __restrict__ alog, float* __restrict__ Pb, float* __restrict__ Sb){
  int c = threadIdx.x;
  int k = blockIdx.x % NCHK; int bg = blockIdx.x / NCHK; int g = bg&3;
  float A = -expf(alog[g*CG+c]);
  size_t base = ((size_t)bg*LS + k*CHL)*CG + c;
  size_t lb = (size_t)bg*LS + k*CHL;
  float P=1.f, S=0.f;
  for (int i=0;i<CHL;i++){
    float d  = ldbf(dt + base + (size_t)i*CG);
    float uv = ldbf(u  + base + (size_t)i*CG);
    float a  = expf(d*A);
    S = a*S + d*Bs[lb+i]*uv; P *= a;
  }
  size_t o = ((size_t)bg*NCHK + k)*CG + c;
  Pb[o]=P; Sb[o]=S;
}

// pass 2: sequential combine of chunk summaries -> h_in per chunk
// NOTE: after this kernel Pb/Sb are dead; the bf16 weight buffer overlays them.
__global__ __launch_bounds__(64) void k_scan2(const float* __restrict__ Pb,
    const float* __restrict__ Sb, float* __restrict__ Hin){
  int c = threadIdx.x; int bg = blockIdx.x;
  float h = 0.f;
  for (int k=0;k<NCHK;k++){
    size_t o = ((size_t)bg*NCHK + k)*CG + c;
    Hin[o] = h;
    h = Pb[o]*h + Sb[o];
  }
}

// convert proj/fc1/fc2 weights to bf16 into wb (overlaid on dead Pb/Sb)
__global__ __launch_bounds__(256) void k_w2b(const float* __restrict__ pw,
    const float* __restrict__ f1w, const float* __restrict__ f2w,
    bf16* __restrict__ wb){
  int i = blockIdx.x*256 + threadIdx.x;   // grid covers 589824 exactly
  float v;
  if (i < 65536)       v = pw[i];
  else if (i < 327680) v = f1w[i-65536];
  else                 v = f2w[i-327680];
  wb[i] = __float2bfloat16(v);
}

// pass 3: final scan + y = h*Cs + Dp*u, fused out-norm LN, silu(z) mult, inverse map
__global__ __launch_bounds__(64) void k_scan3(const bf16* __restrict__ dt,
    const bf16* __restrict__ u, const float* __restrict__ Bs,
    const float* __restrict__ Cs, const float* __restrict__ Hin,
    const float* __restrict__ sz, const float* __restrict__ alog,
    const float* __restrict__ Dpp, const float* __restrict__ onw,
    const float* __restrict__ onb, bf16* __restrict__ ymid){
  int c = threadIdx.x;
  int k = blockIdx.x % NCHK; int bg = blockIdx.x / NCHK;
  int b = bg>>2, g = bg&3;
  float A  = -expf(alog[g*CG+c]);
  float dp = Dpp[g*CG+c];
  float wq = onw[g*CG+c], bq = onb[g*CG+c];
  float h = Hin[((size_t)bg*NCHK + k)*CG + c];
  for (int i=0;i<CHL;i++){
    int l = k*CHL + i;
    size_t idx = ((size_t)bg*LS + l)*CG + c;
    float d = ldbf(dt+idx), uv = ldbf(u+idx);
    float a = expf(d*A);
    h = a*h + d*Bs[(size_t)bg*LS+l]*uv;
    float y = h*Cs[(size_t)bg*LS+l] + dp*uv;
    float s = wsum64(y), s2 = wsum64(y*y);
    float m = s*(1.f/CG), var = s2*(1.f/CG) - m*m;
    float yn = (y-m)*rsqrtf(var+EPSL)*wq + bq;
    int n;
    if (g==0) n = l;
    else if (g==1) n = LS-1-l;
    else { int lt=(g==2)? l : (LS-1-l); n = (lt%HH)*WW + (lt/HH); }
    float szv = sz[((size_t)bg*LS + n)*CG + c];
    ymid[((size_t)b*LS + n)*CH + g*CG + c] = __float2bfloat16(yn*szv);
  }
}

// out_proj (64x64 reg-cached) + skip*xn*gate + LN(norm1) -> ymln (bf16)
__global__ __launch_bounds__(256) void k_mix(const bf16* __restrict__ ymid,
    const bf16* __restrict__ xn, const float* __restrict__ gate,
    const float* __restrict__ opw, const float* __restrict__ skip,
    const float* __restrict__ n1w, const float* __restrict__ n1b,
    bf16* __restrict__ ymln){
  int t = threadIdx.x; int g = t>>6, i = t&63;
  int b = blockIdx.x / (LS/8); int nt = blockIdx.x % (LS/8);
  float Wr[CG];
  const float* wp = opw + (size_t)(g*CG + i)*CG;
  #pragma unroll
  for (int k=0;k<CG;k++) Wr[k]=wp[k];
  float ss = skip[0];
  float gv = gate[b*CH + t];
  float w1 = n1w[t], b1 = n1b[t];
  __shared__ float row[CH];
  __shared__ float r1s[4], r2s[4];
  for (int r=0;r<8;r++){
    int n = nt*8 + r;
    __syncthreads();
    row[t] = ldbf(ymid + ((size_t)b*LS + n)*CH + t);
    __syncthreads();
    float o = 0.f;
    const float* rp = &row[g*CG];
    #pragma unroll
    for (int k=0;k<CG;k++) o += Wr[k]*rp[k];
    float val = o*ss*ldbf(xn + ((size_t)b*LS+n)*CH + t)*gv;
    float s = wsum64(val), s2 = wsum64(val*val);
    if ((t&63)==0){ r1s[t>>6]=s; r2s[t>>6]=s2; }
    __syncthreads();
    float S  = r1s[0]+r1s[1]+r1s[2]+r1s[3];
    float S2 = r2s[0]+r2s[1]+r2s[2]+r2s[3];
    float m = S*(1.f/CH), var = S2*(1.f/CH)-m*m;
    ymln[((size_t)b*LS+n)*CH + t] = __float2bfloat16((val-m)*rsqrtf(var+EPSL)*w1 + b1);
  }
}

// MFMA NT GEMM: C[m,n] = sum_k A[m,k]*Bw[n,k] (+bias[n]) (+resid[m,n])
// A bf16 (M,K) lda=K; Bw bf16 (N rows, ldb stride); 128x128 tile, BK=64,
// 4 waves (2x2), 16x16x32 MFMA, global_load_lds staging, XOR-swizzled LDS.
template<int OBF16>
__global__ __launch_bounds__(256) void k_mgemm(const bf16* __restrict__ A,
    const bf16* __restrict__ Bw, int ldb, const float* __restrict__ bias,
    const float* __restrict__ resid, void* __restrict__ Cp,
    int M, int N, int K){
  __shared__ bf16 As[128*64] __attribute__((aligned(16)));
  __shared__ bf16 Bs[128*64] __attribute__((aligned(16)));
  int t = threadIdx.x;
  int l = t & 63, w = t >> 6;
  int wm = w >> 1, wn = w & 1;
  int m0 = blockIdx.y * 128, n0 = blockIdx.x * 128;
  f32x4 acc[4][4];
  #pragma unroll
  for (int i=0;i<4;i++)
    #pragma unroll
    for (int j=0;j<4;j++) acc[i][j] = (f32x4){0.f,0.f,0.f,0.f};

  for (int kt = 0; kt < K; kt += 64){
    // stage tiles: 1024 16B-chunks each, lane-consecutive LDS dest (linear),
    // inverse-swizzled global source (slot kc holds data kc^(row&7))
    #pragma unroll
    for (int j=0;j<4;j++){
      int cid = j*256 + t;
      int row = cid >> 3, kc = cid & 7;
      int kd  = kc ^ (row & 7);
      g2l16(A  + (size_t)(m0+row)*K   + kt + kd*8, (bf16*)As + (size_t)cid*8);
      g2l16(Bw + (size_t)(n0+row)*ldb + kt + kd*8, (bf16*)Bs + (size_t)cid*8);
    }
    __syncthreads();
    #pragma unroll
    for (int ks=0;ks<2;ks++){
      bf16x8 af[4], bfr[4];
      int kc = ks*4 + (l>>4);
      #pragma unroll
      for (int fi=0;fi<4;fi++){
        int row = wm*64 + fi*16 + (l&15);
        af[fi] = *(const bf16x8*)(As + row*64 + (kc ^ (row&7))*8);
      }
      #pragma unroll
      for (int fj=0;fj<4;fj++){
        int col = wn*64 + fj*16 + (l&15);
        bfr[fj] = *(const bf16x8*)(Bs + col*64 + (kc ^ (col&7))*8);
      }
      #pragma unroll
      for (int fi=0;fi<4;fi++)
        #pragma unroll
        for (int fj=0;fj<4;fj++)
          acc[fi][fj] = __builtin_amdgcn_mfma_f32_16x16x32_bf16(af[fi], bfr[fj], acc[fi][fj], 0,0,0);
    }
    __syncthreads();
  }
  // epilogue: C/D layout col=lane&15, row=(lane>>4)*4+reg
  #pragma unroll
  for (int fi=0;fi<4;fi++){
    #pragma unroll
    for (int fj=0;fj<4;fj++){
      int colb = n0 + wn*64 + fj*16 + (l&15);
      float bv = bias ? bias[colb] : 0.f;
      #pragma unroll
      for (int r=0;r<4;r++){
        size_t mrow = (size_t)m0 + wm*64 + fi*16 + (l>>4)*4 + r;
        size_t off = mrow*(size_t)N + colb;
        float v = acc[fi][fj][r] + bv;
        if (resid) v += resid[off];
        if (OBF16) ((bf16*)Cp)[off] = __float2bfloat16(v);
        else       ((float*)Cp)[off] = v;
      }
    }
  }
}

// depthwise 3x3 on one hidden-quarter (256 ch) + exact GELU, bf16 in/out
__global__ __launch_bounds__(256) void k_dwgelu(const bf16* __restrict__ h1,
    const float* __restrict__ dww, const float* __restrict__ dwb, int q,
    bf16* __restrict__ h2){
  int lin = blockIdx.x;
  int b = lin / LS, n = lin % LS;
  int hh2 = n/WW, ww2 = n%WW;
  int t = threadIdx.x;
  int ch = q*256 + t;
  size_t rb = (size_t)b*LS;
  float acc = dwb[ch];
  #pragma unroll
  for (int dy=-1;dy<=1;dy++){
    int y=hh2+dy; if (y<0||y>=HH) continue;
    #pragma unroll
    for (int dx=-1;dx<=1;dx++){
      int x2=ww2+dx; if (x2<0||x2>=WW) continue;
      acc += ldbf(h1 + (rb + y*WW + x2)*CH + t) * dww[(ch*3+dy+1)*3 + dx+1];
    }
  }
  float gel = 0.5f*acc*(1.f + erff(acc*0.7071067811865475f));
  h2[(rb + n)*CH + t] = __float2bfloat16(gel);
}

extern "C" void kernel_launch(void* const* d_in, const int* in_sizes, int n_in,
                              void* d_out, int out_size, void* d_ws, size_t ws_size,
                              hipStream_t stream){
  const float* x    = (const float*)d_in[0];
  const float* n1w  = (const float*)d_in[1];
  const float* n1b  = (const float*)d_in[2];
  const float* fcw  = (const float*)d_in[3];
  const float* fcb  = (const float*)d_in[4];
  const float* caw  = (const float*)d_in[5];
  const float* skip = (const float*)d_in[6];
  const float* pw   = (const float*)d_in[7];
  const float* pb   = (const float*)d_in[8];
  const float* ipw  = (const float*)d_in[9];
  const float* cw   = (const float*)d_in[10];
  const float* cb   = (const float*)d_in[11];
  const float* xpw  = (const float*)d_in[12];
  const float* dtw  = (const float*)d_in[13];
  const float* dtb  = (const float*)d_in[14];
  const float* alog = (const float*)d_in[15];
  const float* Dp   = (const float*)d_in[16];
  const float* onw  = (const float*)d_in[17];
  const float* onb  = (const float*)d_in[18];
  const float* opw  = (const float*)d_in[19];
  const float* n2w  = (const float*)d_in[20];
  const float* n2b  = (const float*)d_in[21];
  const float* f1w  = (const float*)d_in[22];
  const float* f1b  = (const float*)d_in[23];
  const float* dww  = (const float*)d_in[24];
  const float* dwb  = (const float*)d_in[25];
  const float* f2w  = (const float*)d_in[26];
  const float* f2b  = (const float*)d_in[27];
  (void)in_sizes; (void)n_in; (void)out_size;

  const size_t HRE = (size_t)B_*LS*CH;   // 12,845,056 elems; bf16 region = 25.7 MB
  bf16* hb   = (bf16*)d_ws;
  bf16* xnb  = hb;             // HR0: xn            -> h1 (quarter)
  bf16* xcp  = hb + HRE;       // HR1: xcpre -> ymid -> h2 (quarter)
  bf16* ub   = hb + 2*HRE;     // HR2: u     -> ymln
  bf16* dtq  = hb + 3*HRE;     // HR3: dt    -> xn2
  float* sm  = (float*)(hb + 4*HRE);
  float* part= sm;             // 131072
  float* gate= sm + 131072;    // 4096
  float* Bs  = sm + 135168;    // 200704
  float* Cs  = sm + 335872;    // 200704
  float* Pb  = sm + 536576;    // 200704
  float* Sb  = sm + 737280;    // 200704
  float* Hin = sm + 937984;    // 200704  (small total = 1,138,688 f32)
  // bf16 weights (589,824 elems = 1.18 MB) overlay dead Pb+Sb after k_scan2
  bf16* wb   = (bf16*)(sm + 536576);
  bf16* pwb  = wb;
  bf16* f1wb = wb + 65536;
  bf16* f2wb = wb + 327680;
  float* szf  = (float*)d_out; // d_out doubles as scratch: sz until scan3,
  float* xnew = (float*)d_out; // then x_new (residual) until the end.

  size_t need = 4*HRE*sizeof(bf16) + (size_t)1138688*sizeof(float); // 107,315,200 B
  if (ws_size < need){
    hipMemcpyAsync(d_out, (const void*)x, HRE*sizeof(float),
                   hipMemcpyDeviceToDevice, stream);
    return;
  }

  const int M = B_*LS;

  k_ln256  <<<M, 256, 0, stream>>>(x, n1w, n1b, xnb);
  k_colmean<<<B_*32, 256, 0, stream>>>(xnb, part);
  k_gate   <<<B_, 256, 0, stream>>>(part, fcw, fcb, caw, gate);
  k_inproj <<<dim3(49, B_*NG), 256, 0, stream>>>(xnb, ipw, xcp, szf);
  k_conv_u <<<B_*NG*(LS/4), 256, 0, stream>>>(xcp, cw, cb, ub);
  k_xdbl   <<<B_*NG*(LS/4), 256, 0, stream>>>(ub, xpw, dtw, dtb, dtq, Bs, Cs);
  k_scan1  <<<B_*NG*NCHK, 64, 0, stream>>>(dtq, ub, Bs, alog, Pb, Sb);
  k_scan2  <<<B_*NG, 64, 0, stream>>>(Pb, Sb, Hin);
  k_w2b    <<<2304, 256, 0, stream>>>(pw, f1w, f2w, wb);   // Pb/Sb dead now
  k_scan3  <<<B_*NG*NCHK, 64, 0, stream>>>(dtq, ub, Bs, Cs, Hin, szf, alog, Dp, onw, onb, xcp);
  k_mix    <<<B_*(LS/8), 256, 0, stream>>>(xcp, xnb, gate, opw, skip, n1w, n1b, ub);
  // proj GEMM: x_new = ymln @ pw^T + pb + x  -> d_out (f32)
  k_mgemm<0><<<dim3(CH/128, M/128), 256, 0, stream>>>(ub, pwb, CH, pb, x, xnew, M, CH, CH);
  // norm2 -> xn2 (bf16, HR3)
  k_ln256  <<<M, 256, 0, stream>>>(xnew, n2w, n2b, dtq);
  // MLP in hidden-quarters of 256: fc1 -> dwconv+gelu -> fc2 accumulate into d_out
  for (int q=0; q<4; ++q){
    k_mgemm<1><<<dim3(256/128, M/128), 256, 0, stream>>>(dtq, f1wb + (size_t)q*65536, CH,
                                                 f1b + q*256, nullptr, xnb, M, 256, CH);
    k_dwgelu <<<B_*LS, 256, 0, stream>>>(xnb, dww, dwb, q, xcp);
    k_mgemm<0><<<dim3(256/128, M/128), 256, 0, stream>>>(xcp, f2wb + q*256, HID,
                                                 (q==0)? f2b : nullptr, xnew, xnew, M, 256, 256);
  }
}